// Round 4
// baseline (201.458 us; speedup 1.0000x reference)
//
#include <hip/hip_runtime.h>
#include <cstdint>

// m=8, n=4096, dx=2, dz=16, grid 64x64 -> M=4096. All I/O fp32.
// Structure: g = gtile*64 + lane. grid dim0 coord g0 is BLOCK-uniform ->
// the distance-skip predicate depends only on (b, gtile, n). Phase A
// compacts surviving n into an LDS list (once per block); phase B iterates
// the list branch-free with 4-deep load batching to hide L2 latency.
#define N_PTS   4096
#define M_GRID  4096
#define DZ      16
#define WAVES   8
#define GPB     64
#define REDSTR  17                // padded LDS stride (floats)
#define SKIP_E0 -20.0f            // exp(-20)=2e-9; skip error < 4e-5 << thr

__global__ __launch_bounds__(WAVES * 64)
void setconv_kernel(const float2* __restrict__ x2,     // [8*4096]
                    const float4* __restrict__ z4,     // [8*4096*4]
                    const float*  __restrict__ lsp,    // [2]
                    const float2* __restrict__ grid2,  // [4096]
                    float2*       __restrict__ outx,   // x_grid [8*4096] float2
                    float*        __restrict__ outz)   // z_grid [8*4096*16]
{
    __shared__ int   list[N_PTS];            // survivor n-indices (16 KB)
    __shared__ int   cnt;
    __shared__ float red[(WAVES - 1) * GPB * REDSTR];

    const int lane  = threadIdx.x & 63;
    const int w     = threadIdx.x >> 6;
    const int gtile = blockIdx.x;            // 0..63  (grid row)
    const int b     = blockIdx.y;            // 0..7
    const int g     = gtile * GPB + lane;

    // lengthscale = 1e-5 + softplus(param)  (stable softplus)
    float p0 = lsp[0], p1 = lsp[1];
    float sp0 = (p0 > 0.f) ? (p0 + log1pf(expf(-p0))) : log1pf(expf(p0));
    float sp1 = (p1 > 0.f) ? (p1 + log1pf(expf(-p1))) : log1pf(expf(p1));
    float ls0 = 1e-5f + sp0, ls1 = 1e-5f + sp1;
    const float q0 = -0.5f / (ls0 * ls0);    // wgt = exp(q0*d0^2 + q1*d1^2)
    const float q1 = -0.5f / (ls1 * ls1);

    const float2 gv = grid2[g];
    const float g0 = gv.x;                   // block-uniform (row coord)
    const float g1 = gv.y;                   // per-lane (col coord)

    // fused x_grid write: x_grid[b,g,:] = grid[g,:]
    if (w == 0) outx[(size_t)b * M_GRID + g] = gv;

    if (threadIdx.x == 0) cnt = 0;
    __syncthreads();

    const float2* xb = x2 + b * N_PTS;
    const float4* zb = z4 + (size_t)b * N_PTS * 4;

    // ---- Phase A: block-wide survivor compaction (coalesced x reads) ----
    for (int t = threadIdx.x; t < N_PTS; t += WAVES * 64) {
        float d0 = g0 - xb[t].x;
        bool keep = (q0 * d0 * d0 >= SKIP_E0);
        unsigned long long m = __ballot(keep);
        int base = 0;
        if (lane == 0 && m) base = atomicAdd(&cnt, __popcll(m));
        base = __shfl(base, 0);
        if (keep) {
            int off = __popcll(m & ((1ull << lane) - 1ull));
            list[base + off] = t;
        }
    }
    __syncthreads();
    const int C = cnt;

    float acc[DZ];
#pragma unroll
    for (int d = 0; d < DZ; ++d) acc[d] = 0.f;

    // ---- Phase B: branch-free survivor loop, 4-wide load batching ----
    int s = (w * C) / WAVES;
    const int e = ((w + 1) * C) / WAVES;

#define FMA16(W, A0, A1, A2, A3)                                   \
    acc[0]  = fmaf(W, A0.x, acc[0]);  acc[1]  = fmaf(W, A0.y, acc[1]);  \
    acc[2]  = fmaf(W, A0.z, acc[2]);  acc[3]  = fmaf(W, A0.w, acc[3]);  \
    acc[4]  = fmaf(W, A1.x, acc[4]);  acc[5]  = fmaf(W, A1.y, acc[5]);  \
    acc[6]  = fmaf(W, A1.z, acc[6]);  acc[7]  = fmaf(W, A1.w, acc[7]);  \
    acc[8]  = fmaf(W, A2.x, acc[8]);  acc[9]  = fmaf(W, A2.y, acc[9]);  \
    acc[10] = fmaf(W, A2.z, acc[10]); acc[11] = fmaf(W, A2.w, acc[11]); \
    acc[12] = fmaf(W, A3.x, acc[12]); acc[13] = fmaf(W, A3.y, acc[13]); \
    acc[14] = fmaf(W, A3.z, acc[14]); acc[15] = fmaf(W, A3.w, acc[15])

    for (; s + 4 <= e; s += 4) {
        int n0 = list[s], n1 = list[s + 1], n2 = list[s + 2], n3 = list[s + 3];
        // issue ALL loads first (independent -> overlapped in flight)
        float2 xv0 = xb[n0], xv1 = xb[n1], xv2 = xb[n2], xv3 = xb[n3];
        const float4* zr0 = zb + (size_t)n0 * 4;
        const float4* zr1 = zb + (size_t)n1 * 4;
        const float4* zr2 = zb + (size_t)n2 * 4;
        const float4* zr3 = zb + (size_t)n3 * 4;
        float4 a0 = zr0[0], a1 = zr0[1], a2 = zr0[2], a3 = zr0[3];
        float4 b0 = zr1[0], b1 = zr1[1], b2 = zr1[2], b3 = zr1[3];
        float4 c0 = zr2[0], c1 = zr2[1], c2 = zr2[2], c3 = zr2[3];
        float4 d0v = zr3[0], d1v = zr3[1], d2v = zr3[2], d3v = zr3[3];

        float t0 = g0 - xv0.x, u0 = g1 - xv0.y;
        float t1 = g0 - xv1.x, u1 = g1 - xv1.y;
        float t2 = g0 - xv2.x, u2 = g1 - xv2.y;
        float t3 = g0 - xv3.x, u3 = g1 - xv3.y;
        float w0 = __expf(fmaf(q1 * u0, u0, q0 * t0 * t0));
        float w1 = __expf(fmaf(q1 * u1, u1, q0 * t1 * t1));
        float w2 = __expf(fmaf(q1 * u2, u2, q0 * t2 * t2));
        float w3 = __expf(fmaf(q1 * u3, u3, q0 * t3 * t3));

        FMA16(w0, a0, a1, a2, a3);
        FMA16(w1, b0, b1, b2, b3);
        FMA16(w2, c0, c1, c2, c3);
        FMA16(w3, d0v, d1v, d2v, d3v);
    }
    for (; s < e; ++s) {
        int n = list[s];
        float2 xv = xb[n];
        const float4* zr = zb + (size_t)n * 4;
        float4 a0 = zr[0], a1 = zr[1], a2 = zr[2], a3 = zr[3];
        float t = g0 - xv.x, u = g1 - xv.y;
        float wgt = __expf(fmaf(q1 * u, u, q0 * t * t));
        FMA16(wgt, a0, a1, a2, a3);
    }
#undef FMA16

    // ---- cross-wave reduction ----
    if (w > 0) {
        float* dst = red + ((w - 1) * GPB + lane) * REDSTR;
#pragma unroll
        for (int d = 0; d < DZ; ++d) dst[d] = acc[d];
    }
    __syncthreads();
    if (w == 0) {
#pragma unroll
        for (int j = 0; j < WAVES - 1; ++j) {
            const float* src = red + (j * GPB + lane) * REDSTR;
#pragma unroll
            for (int d = 0; d < DZ; ++d) acc[d] += src[d];
        }
        float4* op = reinterpret_cast<float4*>(outz) + ((size_t)(b * M_GRID + g) * 4);
        op[0] = make_float4(acc[0],  acc[1],  acc[2],  acc[3]);
        op[1] = make_float4(acc[4],  acc[5],  acc[6],  acc[7]);
        op[2] = make_float4(acc[8],  acc[9],  acc[10], acc[11]);
        op[3] = make_float4(acc[12], acc[13], acc[14], acc[15]);
    }
}

extern "C" void kernel_launch(void* const* d_in, const int* in_sizes, int n_in,
                              void* d_out, int out_size, void* d_ws, size_t ws_size,
                              hipStream_t stream) {
    // inputs (all fp32): x [8,4096,2], z [8,4096,16], lengthscale_param [2],
    // grid [64,64,2]. output: x_grid (65536 f32) then z_grid (524288 f32).
    const float2* x2    = (const float2*)d_in[0];
    const float4* z4    = (const float4*)d_in[1];
    const float*  lsp   = (const float*)d_in[2];
    const float2* grid2 = (const float2*)d_in[3];
    float* out = (float*)d_out;

    hipLaunchKernelGGL(setconv_kernel, dim3(64, 8), dim3(WAVES * 64), 0, stream,
                       x2, z4, lsp, grid2, (float2*)out, out + 65536);
}

// Round 5
// 104.100 us; speedup vs baseline: 1.9352x; 1.9352x over previous
//
#include <hip/hip_runtime.h>
#include <cstdint>

// m=8, n=4096, dx=2, dz=16, grid 64x64 -> M=4096. All I/O fp32.
// R4 structure: grid(64 gtile, 8 batch, 4 n-split), 256-thread blocks.
//  - g0 (grid row coord) is block-uniform -> skip predicate per n only.
//  - Phase A: compact survivor indices + x values into LDS (ballot scan).
//  - Phase B: double-buffered cooperative staging of survivor z rows into
//    LDS (coalesced, independent loads) + branch-free compute from LDS.
//  - Partials to d_ws [4][8][4096][16] f32; combine kernel sums + x_grid.
#define N_PTS   4096
#define M_GRID  4096
#define SPLITS  4
#define NS      (N_PTS / SPLITS)    // 1024 points per block's n-range
#define CHUNK   64                  // survivor rows per staged LDS chunk
#define REDSTR  17
#define SKIP_E0 -20.0f              // exp(-20)=2e-9; skip error < 4e-5

__global__ __launch_bounds__(256)
void setconv_partial(const float2* __restrict__ x2,     // [8*4096]
                     const float4* __restrict__ z4,     // [8*4096*4]
                     const float*  __restrict__ lsp,    // [2]
                     const float2* __restrict__ grid2,  // [4096]
                     float*        __restrict__ ws)     // [4][8][4096][16]
{
    __shared__ int    list[NS];             // survivor n (local to range), 4 KB
    __shared__ float2 xs[NS];               // survivor x, 8 KB
    __shared__ float4 zbuf[2][CHUNK * 4];   // staged z rows, 2 x 4 KB
    __shared__ float  red[3 * 64 * REDSTR]; // cross-wave partials, ~12.8 KB
    __shared__ int    cnt;

    const int tid   = threadIdx.x;
    const int lane  = tid & 63;
    const int w     = tid >> 6;             // wave 0..3
    const int gtile = blockIdx.x;           // 0..63 (grid row; g0 uniform)
    const int b     = blockIdx.y;           // 0..7
    const int s     = blockIdx.z;           // 0..3 (n-split)

    // lengthscale = 1e-5 + softplus(param)
    float p0 = lsp[0], p1 = lsp[1];
    float sp0 = (p0 > 0.f) ? (p0 + log1pf(expf(-p0))) : log1pf(expf(p0));
    float sp1 = (p1 > 0.f) ? (p1 + log1pf(expf(-p1))) : log1pf(expf(p1));
    float ls0 = 1e-5f + sp0, ls1 = 1e-5f + sp1;
    const float q0 = -0.5f / (ls0 * ls0);   // wgt = exp(q0*d0^2 + q1*d1^2)
    const float q1 = -0.5f / (ls1 * ls1);

    const int   g  = gtile * 64 + lane;
    const float2 gv = grid2[g];
    const float g0 = gv.x;                  // block-uniform
    const float g1 = gv.y;                  // per-lane

    if (tid == 0) cnt = 0;
    __syncthreads();

    const float2* xb = x2 + b * N_PTS + s * NS;
    const float4* zb = z4 + ((size_t)b * N_PTS + s * NS) * 4;

    // ---- Phase A: compact survivors of this n-range ----
    for (int t = tid; t < NS; t += 256) {
        float2 xv = xb[t];
        float d0 = g0 - xv.x;
        bool keep = (q0 * d0 * d0 >= SKIP_E0);
        unsigned long long m = __ballot(keep);
        int base = 0;
        if (lane == 0 && m) base = atomicAdd(&cnt, __popcll(m));
        base = __shfl(base, 0);
        if (keep) {
            int off = __popcll(m & ((1ull << lane) - 1ull));
            list[base + off] = t;
            xs[base + off]   = xv;
        }
    }
    __syncthreads();
    const int C    = cnt;
    const int Cpad = (C + CHUNK - 1) & ~(CHUNK - 1);
    for (int t = C + tid; t < Cpad; t += 256) {   // sentinel pad -> wgt = 0
        list[t] = 0;
        xs[t]   = make_float2(1e30f, 1e30f);
    }
    __syncthreads();

    float acc[16];
#pragma unroll
    for (int d = 0; d < 16; ++d) acc[d] = 0.f;

    const int nchunk = Cpad / CHUNK;

    // stage chunk ci into zbuf[bufi]: thread t -> row ci*64+(t>>2), qword t&3
    auto stage = [&](int ci, int bufi) {
        int r = ci * CHUNK + (tid >> 2);
        int n = list[r];
        zbuf[bufi][(tid >> 2) * 4 + (tid & 3)] = zb[(size_t)n * 4 + (tid & 3)];
    };

    if (nchunk > 0) stage(0, 0);
    __syncthreads();

    for (int ci = 0; ci < nchunk; ++ci) {
        const int cur = ci & 1;
        if (ci + 1 < nchunk) stage(ci + 1, cur ^ 1);

        const int base = ci * CHUNK + w * (CHUNK / 4);
#pragma unroll 4
        for (int i = 0; i < CHUNK / 4; ++i) {
            const int j = base + i;                 // survivor index (uniform)
            float2 xv = xs[j];                      // broadcast LDS read
            float t0 = g0 - xv.x;
            float u  = g1 - xv.y;
            float wgt = __expf(fmaf(q1 * u, u, q0 * t0 * t0));
            const float4* zr = &zbuf[cur][(w * (CHUNK / 4) + i) * 4];
            float4 a0 = zr[0], a1 = zr[1], a2 = zr[2], a3 = zr[3];
            acc[0]  = fmaf(wgt, a0.x, acc[0]);  acc[1]  = fmaf(wgt, a0.y, acc[1]);
            acc[2]  = fmaf(wgt, a0.z, acc[2]);  acc[3]  = fmaf(wgt, a0.w, acc[3]);
            acc[4]  = fmaf(wgt, a1.x, acc[4]);  acc[5]  = fmaf(wgt, a1.y, acc[5]);
            acc[6]  = fmaf(wgt, a1.z, acc[6]);  acc[7]  = fmaf(wgt, a1.w, acc[7]);
            acc[8]  = fmaf(wgt, a2.x, acc[8]);  acc[9]  = fmaf(wgt, a2.y, acc[9]);
            acc[10] = fmaf(wgt, a2.z, acc[10]); acc[11] = fmaf(wgt, a2.w, acc[11]);
            acc[12] = fmaf(wgt, a3.x, acc[12]); acc[13] = fmaf(wgt, a3.y, acc[13]);
            acc[14] = fmaf(wgt, a3.z, acc[14]); acc[15] = fmaf(wgt, a3.w, acc[15]);
        }
        __syncthreads();
    }

    // ---- cross-wave reduction (4 waves) ----
    if (w > 0) {
        float* dst = red + ((w - 1) * 64 + lane) * REDSTR;
#pragma unroll
        for (int d = 0; d < 16; ++d) dst[d] = acc[d];
    }
    __syncthreads();
    if (w == 0) {
#pragma unroll
        for (int j = 0; j < 3; ++j) {
            const float* src = red + (j * 64 + lane) * REDSTR;
#pragma unroll
            for (int d = 0; d < 16; ++d) acc[d] += src[d];
        }
        float4* ws4 = reinterpret_cast<float4*>(ws);
        size_t pbase = (size_t)s * 131072 + ((size_t)b * M_GRID + g) * 4;
        ws4[pbase + 0] = make_float4(acc[0],  acc[1],  acc[2],  acc[3]);
        ws4[pbase + 1] = make_float4(acc[4],  acc[5],  acc[6],  acc[7]);
        ws4[pbase + 2] = make_float4(acc[8],  acc[9],  acc[10], acc[11]);
        ws4[pbase + 3] = make_float4(acc[12], acc[13], acc[14], acc[15]);
    }
}

// out = [x_grid 16384 float4][z_grid 131072 float4]; z = sum of 4 partials.
__global__ __launch_bounds__(256)
void combine_kernel(const float4* __restrict__ ws4,
                    const float4* __restrict__ grid4,   // 2048 float4
                    float4*       __restrict__ out4)
{
    int idx = blockIdx.x * 256 + threadIdx.x;           // < 147456
    if (idx < 16384) {
        out4[idx] = grid4[idx & 2047];                  // x_grid broadcast
    } else {
        int i = idx - 16384;                            // < 131072
        float4 a = ws4[i];
        float4 b = ws4[131072 + i];
        float4 c = ws4[262144 + i];
        float4 d = ws4[393216 + i];
        out4[idx] = make_float4(a.x + b.x + c.x + d.x,
                                a.y + b.y + c.y + d.y,
                                a.z + b.z + c.z + d.z,
                                a.w + b.w + c.w + d.w);
    }
}

extern "C" void kernel_launch(void* const* d_in, const int* in_sizes, int n_in,
                              void* d_out, int out_size, void* d_ws, size_t ws_size,
                              hipStream_t stream) {
    // inputs (all fp32): x [8,4096,2], z [8,4096,16], lengthscale_param [2],
    // grid [64,64,2]. output: x_grid (65536 f32) ++ z_grid (524288 f32).
    // workspace: 4 partial z_grids = 8 MB fp32.
    const float2* x2    = (const float2*)d_in[0];
    const float4* z4    = (const float4*)d_in[1];
    const float*  lsp   = (const float*)d_in[2];
    const float2* grid2 = (const float2*)d_in[3];
    float* out = (float*)d_out;
    float* ws  = (float*)d_ws;

    hipLaunchKernelGGL(setconv_partial, dim3(64, 8, SPLITS), dim3(256), 0, stream,
                       x2, z4, lsp, grid2, ws);
    hipLaunchKernelGGL(combine_kernel, dim3(576), dim3(256), 0, stream,
                       (const float4*)ws, (const float4*)grid2, (float4*)out);
}

// Round 6
// 103.165 us; speedup vs baseline: 1.9528x; 1.0091x over previous
//
#include <hip/hip_runtime.h>
#include <cstdint>

// m=8, n=4096, dx=2, dz=16, grid 64x64 -> M=4096. All I/O fp32.
// R5 = R4 dataflow (survivor compaction + double-buffered LDS z staging +
// 4-way n-split partials to ws) with two fixes:
//  - LDS union: 'red' aliases zbuf/list/xs (dead after compute) -> 20.5 KB
//    -> 7 blocks/CU resident (was 4 at 33.8 KB).
//  - gtile swizzle (37 coprime 64): decorrelates consecutive block ids from
//    grid-row position -> per-CU survivor load balance.
#define N_PTS   4096
#define M_GRID  4096
#define SPLITS  4
#define NS      (N_PTS / SPLITS)    // 1024 points per block's n-range
#define CHUNK   64                  // survivor rows per staged LDS chunk
#define REDSTR  17
#define SKIP_E0 -20.0f              // exp(-20)=2e-9; skip error < 4e-5

// LDS layout (manual union):
//   [0      .. 8192 )  zbuf: float4[2][CHUNK*4]   (compute phase)
//   [8192   .. 12288)  list: int[NS]              (compute phase)
//   [12288  .. 20480)  xs:   float2[NS]           (compute phase)
//   [20480  .. 20484)  cnt
//   [0      .. 13056)  red:  float[3*64*REDSTR]   (reduction phase, aliases)
#define SMEM_BYTES 20608

__global__ __launch_bounds__(256, 7)
void setconv_partial(const float2* __restrict__ x2,     // [8*4096]
                     const float4* __restrict__ z4,     // [8*4096*4]
                     const float*  __restrict__ lsp,    // [2]
                     const float2* __restrict__ grid2,  // [4096]
                     float*        __restrict__ ws)     // [4][8][4096][16]
{
    __shared__ __align__(16) char smem[SMEM_BYTES];
    float4* zbuf = reinterpret_cast<float4*>(smem);              // [2][256]
    int*    list = reinterpret_cast<int*>(smem + 8192);          // [NS]
    float2* xs   = reinterpret_cast<float2*>(smem + 12288);      // [NS]
    int*    cntp = reinterpret_cast<int*>(smem + 20480);
    float*  red  = reinterpret_cast<float*>(smem);               // aliases!

    const int tid   = threadIdx.x;
    const int lane  = tid & 63;
    const int w     = tid >> 6;             // wave 0..3
    const int b     = blockIdx.y;           // 0..7
    const int s     = blockIdx.z;           // 0..3 (n-split)
    const int gtile = (37 * blockIdx.x + b) & 63;   // swizzled grid row

    // lengthscale = 1e-5 + softplus(param)
    float p0 = lsp[0], p1 = lsp[1];
    float sp0 = (p0 > 0.f) ? (p0 + log1pf(expf(-p0))) : log1pf(expf(p0));
    float sp1 = (p1 > 0.f) ? (p1 + log1pf(expf(-p1))) : log1pf(expf(p1));
    float ls0 = 1e-5f + sp0, ls1 = 1e-5f + sp1;
    const float q0 = -0.5f / (ls0 * ls0);   // wgt = exp(q0*d0^2 + q1*d1^2)
    const float q1 = -0.5f / (ls1 * ls1);

    const int    g  = gtile * 64 + lane;
    const float2 gv = grid2[g];
    const float  g0 = gv.x;                 // block-uniform (row coord)
    const float  g1 = gv.y;                 // per-lane (col coord)

    if (tid == 0) *cntp = 0;
    __syncthreads();

    const float2* xb = x2 + b * N_PTS + s * NS;
    const float4* zb = z4 + ((size_t)b * N_PTS + s * NS) * 4;

    // ---- Phase A: compact survivors of this n-range ----
    for (int t = tid; t < NS; t += 256) {
        float2 xv = xb[t];
        float d0 = g0 - xv.x;
        bool keep = (q0 * d0 * d0 >= SKIP_E0);
        unsigned long long m = __ballot(keep);
        int base = 0;
        if (lane == 0 && m) base = atomicAdd(cntp, __popcll(m));
        base = __shfl(base, 0);
        if (keep) {
            int off = __popcll(m & ((1ull << lane) - 1ull));
            list[base + off] = t;
            xs[base + off]   = xv;
        }
    }
    __syncthreads();
    const int C    = *cntp;
    const int Cpad = (C + CHUNK - 1) & ~(CHUNK - 1);
    for (int t = C + tid; t < Cpad; t += 256) {   // sentinel pad -> wgt = 0
        list[t] = 0;
        xs[t]   = make_float2(1e30f, 1e30f);
    }
    __syncthreads();

    float acc[16];
#pragma unroll
    for (int d = 0; d < 16; ++d) acc[d] = 0.f;

    const int nchunk = Cpad / CHUNK;

    // stage chunk ci into zbuf[bufi]: thread t -> row ci*64+(t>>2), qword t&3
    auto stage = [&](int ci, int bufi) {
        int r = ci * CHUNK + (tid >> 2);
        int n = list[r];
        zbuf[bufi * (CHUNK * 4) + (tid >> 2) * 4 + (tid & 3)] =
            zb[(size_t)n * 4 + (tid & 3)];
    };

    if (nchunk > 0) stage(0, 0);
    __syncthreads();

    for (int ci = 0; ci < nchunk; ++ci) {
        const int cur = ci & 1;
        if (ci + 1 < nchunk) stage(ci + 1, cur ^ 1);

        const int base = ci * CHUNK + w * (CHUNK / 4);
        const float4* zrow = zbuf + cur * (CHUNK * 4) + w * (CHUNK / 4) * 4;
#pragma unroll 4
        for (int i = 0; i < CHUNK / 4; ++i) {
            float2 xv = xs[base + i];               // broadcast LDS read
            float t0 = g0 - xv.x;
            float u  = g1 - xv.y;
            float wgt = __expf(fmaf(q1 * u, u, q0 * t0 * t0));
            const float4* zr = zrow + i * 4;
            float4 a0 = zr[0], a1 = zr[1], a2 = zr[2], a3 = zr[3];
            acc[0]  = fmaf(wgt, a0.x, acc[0]);  acc[1]  = fmaf(wgt, a0.y, acc[1]);
            acc[2]  = fmaf(wgt, a0.z, acc[2]);  acc[3]  = fmaf(wgt, a0.w, acc[3]);
            acc[4]  = fmaf(wgt, a1.x, acc[4]);  acc[5]  = fmaf(wgt, a1.y, acc[5]);
            acc[6]  = fmaf(wgt, a1.z, acc[6]);  acc[7]  = fmaf(wgt, a1.w, acc[7]);
            acc[8]  = fmaf(wgt, a2.x, acc[8]);  acc[9]  = fmaf(wgt, a2.y, acc[9]);
            acc[10] = fmaf(wgt, a2.z, acc[10]); acc[11] = fmaf(wgt, a2.w, acc[11]);
            acc[12] = fmaf(wgt, a3.x, acc[12]); acc[13] = fmaf(wgt, a3.y, acc[13]);
            acc[14] = fmaf(wgt, a3.z, acc[14]); acc[15] = fmaf(wgt, a3.w, acc[15]);
        }
        __syncthreads();   // also separates compute reads from red aliasing
    }

    // ---- cross-wave reduction (red ALIASES zbuf/list/xs — all dead now) ----
    if (w > 0) {
        float* dst = red + ((w - 1) * 64 + lane) * REDSTR;
#pragma unroll
        for (int d = 0; d < 16; ++d) dst[d] = acc[d];
    }
    __syncthreads();
    if (w == 0) {
#pragma unroll
        for (int j = 0; j < 3; ++j) {
            const float* src = red + (j * 64 + lane) * REDSTR;
#pragma unroll
            for (int d = 0; d < 16; ++d) acc[d] += src[d];
        }
        float4* ws4 = reinterpret_cast<float4*>(ws);
        size_t pbase = (size_t)s * 131072 + ((size_t)b * M_GRID + g) * 4;
        ws4[pbase + 0] = make_float4(acc[0],  acc[1],  acc[2],  acc[3]);
        ws4[pbase + 1] = make_float4(acc[4],  acc[5],  acc[6],  acc[7]);
        ws4[pbase + 2] = make_float4(acc[8],  acc[9],  acc[10], acc[11]);
        ws4[pbase + 3] = make_float4(acc[12], acc[13], acc[14], acc[15]);
    }
}

// out = [x_grid 16384 float4][z_grid 131072 float4]; z = sum of 4 partials.
__global__ __launch_bounds__(256)
void combine_kernel(const float4* __restrict__ ws4,
                    const float4* __restrict__ grid4,   // 2048 float4
                    float4*       __restrict__ out4)
{
    int idx = blockIdx.x * 256 + threadIdx.x;           // < 147456
    if (idx < 16384) {
        out4[idx] = grid4[idx & 2047];                  // x_grid broadcast
    } else {
        int i = idx - 16384;                            // < 131072
        float4 a = ws4[i];
        float4 b = ws4[131072 + i];
        float4 c = ws4[262144 + i];
        float4 d = ws4[393216 + i];
        out4[idx] = make_float4(a.x + b.x + c.x + d.x,
                                a.y + b.y + c.y + d.y,
                                a.z + b.z + c.z + d.z,
                                a.w + b.w + c.w + d.w);
    }
}

extern "C" void kernel_launch(void* const* d_in, const int* in_sizes, int n_in,
                              void* d_out, int out_size, void* d_ws, size_t ws_size,
                              hipStream_t stream) {
    // inputs (all fp32): x [8,4096,2], z [8,4096,16], lengthscale_param [2],
    // grid [64,64,2]. output: x_grid (65536 f32) ++ z_grid (524288 f32).
    // workspace: 4 partial z_grids = 8 MB fp32.
    const float2* x2    = (const float2*)d_in[0];
    const float4* z4    = (const float4*)d_in[1];
    const float*  lsp   = (const float*)d_in[2];
    const float2* grid2 = (const float2*)d_in[3];
    float* out = (float*)d_out;
    float* ws  = (float*)d_ws;

    hipLaunchKernelGGL(setconv_partial, dim3(64, 8, SPLITS), dim3(256), 0, stream,
                       x2, z4, lsp, grid2, ws);
    hipLaunchKernelGGL(combine_kernel, dim3(576), dim3(256), 0, stream,
                       (const float4*)ws, (const float4*)grid2, (float4*)out);
}